// Round 9
// baseline (24.393 us; speedup 1.0000x reference)
//
#include <hip/hip_runtime.h>

#define MARGIN 0.3f
#define ANCHOR 0.5f
#define EPS    1e-8f
#define BJ     256
#define NSLOT  32        // accumulator slots, each on its own 64B line

typedef unsigned long long ull;
typedef __attribute__((ext_vector_type(16))) float f16v;

// ws accumulator layout (all 64B-padded):
//   gsum[k] : ws + k*64            (double)
//   gcnt[k] : ws + 2048 + k*64     (unsigned)
//   arr[k]  : ws + 4096 + k*64     (unsigned)
//   master  : ws + 6144            (unsigned)
//   pairs[N]: ws + 8192            (float2 {s_q, quality} interleaved)

// ---------------- kernel 1: {s_q, quality} pairs + accumulator zero-init -------
__global__ __launch_bounds__(256) void sq_kernel(
        const float* __restrict__ q, const float* __restrict__ d,
        const float* __restrict__ rates, float2* __restrict__ pairs,
        char* __restrict__ acc, int N, int D) {
    int tid = threadIdx.x;
    if (blockIdx.x == 0) {
        if (tid < NSLOT)              *(double*)  (acc + (size_t)tid * 64)               = 0.0;
        else if (tid < 2 * NSLOT)     *(unsigned*)(acc + 2048 + (size_t)(tid - 32) * 64) = 0u;
        else if (tid < 3 * NSLOT)     *(unsigned*)(acc + 4096 + (size_t)(tid - 64) * 64) = 0u;
        else if (tid == 3 * NSLOT)    *(unsigned*)(acc + 6144)                           = 0u;
    }
    int wave = (blockIdx.x * blockDim.x + tid) >> 6;
    int lane = tid & 63;
    if (wave >= N) return;
    const float* row = d + (size_t)wave * (size_t)D;

    float dot = 0.f, dn = 0.f, qn = 0.f;
    for (int it = lane * 4; it < D; it += 256) {
        float4 dv = *(const float4*)(row + it);
        float4 qv = *(const float4*)(q + it);
        dot += dv.x * qv.x + dv.y * qv.y + dv.z * qv.z + dv.w * qv.w;
        dn  += dv.x * dv.x + dv.y * dv.y + dv.z * dv.z + dv.w * dv.w;
        qn  += qv.x * qv.x + qv.y * qv.y + qv.z * qv.z + qv.w * qv.w;
    }
    #pragma unroll
    for (int off = 32; off >= 1; off >>= 1) {
        dot += __shfl_xor(dot, off);
        dn  += __shfl_xor(dn,  off);
        qn  += __shfl_xor(qn,  off);
    }
    if (lane == 0) {
        float den = fmaxf(sqrtf(dn) * sqrtf(qn), EPS);
        pairs[wave] = make_float2(dot / den, fabsf(rates[wave] - ANCHOR));
    }
}

// ------- kernel 2: N^2 pairs; j-data via SMEM pipe into SGPRs (no DS/VMEM) -----
// grid = (N/256, N/BJ). Per 16 j's: 2x s_load_dwordx16 -> 32 SGPRs, then pure
// VALU inner loop (SGPR src0 operands). Count on scalar pipe via ballot/popc.
__global__ __launch_bounds__(256) void pair_kernel(
        const float2* __restrict__ pairs,
        int N, char* __restrict__ acc, float* __restrict__ out, unsigned nblocks) {
    __shared__ double   bsum[4];
    __shared__ unsigned bcnt[4];

    int tid = threadIdx.x;
    int i   = blockIdx.x * blockDim.x + tid;
    int j0  = blockIdx.y * BJ;

    float my_sq = 0.f, my_q = -1.f;           // quality >= 0 -> masks all pairs off
    if (i < N) { float2 p = pairs[i]; my_sq = p.x; my_q = p.y; }
    float a = MARGIN - my_sq;

    float    sum = 0.f;
    unsigned c   = 0;                          // wave-uniform (scalar pipe)
    int jmax = N - j0; if (jmax > BJ) jmax = BJ;

    int g = 0;
    for (; g + 16 <= jmax; g += 16) {
        const float2* p = pairs + j0 + g;
        f16v A, B;
        asm volatile(
            "s_load_dwordx16 %0, %2, 0x0\n\t"
            "s_load_dwordx16 %1, %2, 0x40\n\t"
            "s_waitcnt lgkmcnt(0)"
            : "=&s"(A), "=&s"(B)
            : "s"(p));
        #pragma unroll
        for (int k = 0; k < 8; ++k) {
            float sj = A[2 * k], qj = A[2 * k + 1];
            bool  m = my_q > qj;               // v_cmp (SGPR src0)
            float t = a + sj;                  // v_add (SGPR src0)
            float z = m ? t : 0.f;             // v_cndmask
            sum += fmaxf(z, 0.f);              // v_max + v_add
            c   += (unsigned)__popcll(__ballot(m));   // s_bcnt1 + s_add
        }
        #pragma unroll
        for (int k = 0; k < 8; ++k) {
            float sj = B[2 * k], qj = B[2 * k + 1];
            bool  m = my_q > qj;
            float t = a + sj;
            float z = m ? t : 0.f;
            sum += fmaxf(z, 0.f);
            c   += (unsigned)__popcll(__ballot(m));
        }
    }
    for (; g < jmax; ++g) {                    // generic tail (N % 16 != 0)
        float2 pj = pairs[j0 + g];
        bool  m = my_q > pj.y;
        float t = a + pj.x;
        sum += m ? fmaxf(t, 0.f) : 0.f;
        c   += (unsigned)__popcll(__ballot(m));
    }

    #pragma unroll
    for (int off = 32; off >= 1; off >>= 1)
        sum += __shfl_xor(sum, off);

    int w = tid >> 6;
    if ((tid & 63) == 0) { bsum[w] = (double)sum; bcnt[w] = c; }
    __syncthreads();

    if (tid >= 64) return;

    unsigned last = 0;
    if (tid == 0) {
        double   bs = bsum[0] + bsum[1] + bsum[2] + bsum[3];
        unsigned bc = bcnt[0] + bcnt[1] + bcnt[2] + bcnt[3];
        unsigned bid = blockIdx.y * gridDim.x + blockIdx.x;
        unsigned s   = bid & (NSLOT - 1);

        // slot accumulate (distinct 64B lines; <=32 RMWs per line)
        double   old  = atomicAdd((double*)  (acc + (size_t)s * 64), bs);
        unsigned oldc = atomicAdd((unsigned*)(acc + 2048 + (size_t)s * 64), bc);
        // consume returns -> both RMWs are PERFORMED at the device-coherent
        // point before the arrival increment issues (fence-free ordering).
        asm volatile("" :: "v"(__double2hiint(old)), "v"(__double2loint(old)), "v"(oldc));

        unsigned gsz = (nblocks > s) ? ((nblocks - 1u - s) / NSLOT + 1u) : 0u;
        unsigned pa  = atomicAdd((unsigned*)(acc + 4096 + (size_t)s * 64), 1u);
        if (pa == gsz - 1u) {                       // slot winner
            asm volatile("" :: "v"(pa));
            unsigned nslots = (nblocks < NSLOT) ? nblocks : NSLOT;
            unsigned pm = atomicAdd((unsigned*)(acc + 6144), 1u);
            last = (pm == nslots - 1u) ? 1u : 0u;   // overall last block
        }
    }
    last = __shfl(last, 0);
    if (last) {
        double s = 0.0; ull c2 = 0ull;
        if (tid < NSLOT) {
            s  = atomicAdd((double*)  (acc + (size_t)tid * 64), 0.0);
            c2 = (ull)atomicAdd((unsigned*)(acc + 2048 + (size_t)tid * 64), 0u);
        }
        #pragma unroll
        for (int off = 16; off >= 1; off >>= 1) {
            s  += __shfl_xor(s,  off);
            c2 += __shfl_xor(c2, off);
        }
        if (tid == 0) {
            if (c2 < 1ull) c2 = 1ull;
            out[0] = (float)(s / (double)c2);
        }
    }
}

extern "C" void kernel_launch(void* const* d_in, const int* in_sizes, int n_in,
                              void* d_out, int out_size, void* d_ws, size_t ws_size,
                              hipStream_t stream) {
    const float* q_emb  = (const float*)d_in[0];
    const float* d_embs = (const float*)d_in[1];
    // d_in[2] = c_emb: computed-but-unused in the reference; skipped.
    const float* rates  = (const float*)d_in[3];

    int D = in_sizes[0];
    int N = in_sizes[3];

    char*   acc   = (char*)d_ws;
    float2* pairs = (float2*)(acc + 8192);
    float*  out   = (float*)d_out;

    int rows_per_block = 256 / 64;   // 4 waves/block, 1 row/wave
    sq_kernel<<<(N + rows_per_block - 1) / rows_per_block, 256, 0, stream>>>(
        q_emb, d_embs, rates, pairs, acc, N, D);

    dim3 grid((N + 255) / 256, (N + BJ - 1) / BJ);
    pair_kernel<<<grid, 256, 0, stream>>>(pairs, N, acc, out,
                                          grid.x * grid.y);
}